// Round 1
// baseline (2413.461 us; speedup 1.0000x reference)
//
#include <hip/hip_runtime.h>
#include <hip/hip_bf16.h>

// Problem constants
// B=4, N=2048, DIM=512, H=8, DH=64, ORDER=3, TOPK=64, INNER=512
#define SLOTS 80   // sparse slots per row (64 + tie headroom)

// ---------------------------------------------------------------------------
// K1/K4: fp32 tiled GEMM with bias: C = A(MxK) @ B(KxN) + bias(N)
// BM=BN=64, BK=16, 256 threads, 4x4 per thread
// ---------------------------------------------------------------------------
__global__ __launch_bounds__(256)
void sgemm_bias(const float* __restrict__ A, const float* __restrict__ Bm,
                const float* __restrict__ bias, float* __restrict__ C,
                int M, int N, int K)
{
    __shared__ float As[16][68];   // [k][m], padded for 16B-aligned float4
    __shared__ float Bs[16][68];   // [k][n]
    const int t  = threadIdx.x;
    const int tx = t & 15, ty = t >> 4;
    const int bm = blockIdx.y << 6, bn = blockIdx.x << 6;
    const int arow = t >> 2, akq = (t & 3) << 2;
    const int bkr  = t >> 4, bnq = (t & 15) << 2;

    float acc[4][4] = {};

    for (int k0 = 0; k0 < K; k0 += 16) {
        float4 av = *(const float4*)&A[(size_t)(bm + arow) * K + k0 + akq];
        float4 bv = *(const float4*)&Bm[(size_t)(k0 + bkr) * N + bn + bnq];
        __syncthreads();
        As[akq + 0][arow] = av.x;
        As[akq + 1][arow] = av.y;
        As[akq + 2][arow] = av.z;
        As[akq + 3][arow] = av.w;
        *(float4*)&Bs[bkr][bnq] = bv;
        __syncthreads();
#pragma unroll
        for (int kk = 0; kk < 16; ++kk) {
            float4 a = *(const float4*)&As[kk][ty << 2];
            float4 b = *(const float4*)&Bs[kk][tx << 2];
            float ar[4] = {a.x, a.y, a.z, a.w};
            float br[4] = {b.x, b.y, b.z, b.w};
#pragma unroll
            for (int i = 0; i < 4; ++i)
#pragma unroll
                for (int j = 0; j < 4; ++j)
                    acc[i][j] = fmaf(ar[i], br[j], acc[i][j]);
        }
    }
#pragma unroll
    for (int i = 0; i < 4; ++i)
#pragma unroll
        for (int j = 0; j < 4; ++j)
            C[(size_t)(bm + (ty << 2) + i) * N + bn + (tx << 2) + j] =
                acc[i][j] + bias[bn + (tx << 2) + j];
}

// ---------------------------------------------------------------------------
// K2: per-(b,h), 16 rows/block: scores = q@k^T * 0.125 into LDS, then exact
// top-64 (keep ties) via uint-bisection, softmax, sparse compaction.
// LDS: S 131072 + ks 20480 + qs 4352 = 155904 B  (gfx950 has 160 KiB)
// ---------------------------------------------------------------------------
__global__ __launch_bounds__(256)
void scores_topk(const float* __restrict__ qkv, float* __restrict__ svals,
                 unsigned short* __restrict__ sidx, int* __restrict__ scnt)
{
    __shared__ float S[16][2048];
    __shared__ float ks[256][20];   // [col][d-chunk of 16], pad 20 for banks
    __shared__ float qs[16][68];

    const int t    = threadIdx.x;
    const int lane = t & 63;
    const int wid  = t >> 6;
    const int bh   = blockIdx.y;
    const int b    = bh >> 3, h = bh & 7;
    const int r0   = blockIdx.x << 4;
    const size_t rowbase = (size_t)b * 2048;
    const int qoff = h << 6;
    const int koff = 512 + (h << 6);

    // stage q rows (16 x 64)
    {
        int row = t >> 4, dq = (t & 15) << 2;
        *(float4*)&qs[row][dq] =
            *(const float4*)&qkv[(rowbase + r0 + row) * 1536 + qoff + dq];
    }

    const int cbase = t >> 2;        // 0..63
    const int f4    = (t & 3) << 2;  // 0,4,8,12
    const int rg4   = wid << 2;      // wave's 4 rows

    // software-pipelined k staging: preload tile 0
    float4 r4[4];
#pragma unroll
    for (int s = 0; s < 4; ++s)
        r4[s] = *(const float4*)&qkv[(rowbase + cbase + (s << 6)) * 1536 + koff + f4];

    float acc[4][4];

    // 32 tiles: 8 col-tiles (256 cols) x 4 d-chunks (16 d)
    for (int tt = 0; tt < 32; ++tt) {
        __syncthreads();
#pragma unroll
        for (int s = 0; s < 4; ++s)
            *(float4*)&ks[cbase + (s << 6)][f4] = r4[s];
        __syncthreads();
        if (tt < 31) {
            const int c0n = ((tt + 1) >> 2) << 8;
            const int d0n = ((tt + 1) & 3) << 4;
#pragma unroll
            for (int s = 0; s < 4; ++s)
                r4[s] = *(const float4*)
                    &qkv[(rowbase + c0n + cbase + (s << 6)) * 1536 + koff + d0n + f4];
        }
        const int d0 = (tt & 3) << 4;
        if ((tt & 3) == 0) {
#pragma unroll
            for (int i = 0; i < 4; ++i)
#pragma unroll
                for (int j = 0; j < 4; ++j) acc[i][j] = 0.f;
        }
#pragma unroll
        for (int dd = 0; dd < 16; dd += 4) {
            float4 a0 = *(const float4*)&qs[rg4 + 0][d0 + dd];
            float4 a1 = *(const float4*)&qs[rg4 + 1][d0 + dd];
            float4 a2 = *(const float4*)&qs[rg4 + 2][d0 + dd];
            float4 a3 = *(const float4*)&qs[rg4 + 3][d0 + dd];
#pragma unroll
            for (int j = 0; j < 4; ++j) {
                float4 bv = *(const float4*)&ks[lane + (j << 6)][dd];
                acc[0][j] = fmaf(a0.x, bv.x, fmaf(a0.y, bv.y, fmaf(a0.z, bv.z, fmaf(a0.w, bv.w, acc[0][j]))));
                acc[1][j] = fmaf(a1.x, bv.x, fmaf(a1.y, bv.y, fmaf(a1.z, bv.z, fmaf(a1.w, bv.w, acc[1][j]))));
                acc[2][j] = fmaf(a2.x, bv.x, fmaf(a2.y, bv.y, fmaf(a2.z, bv.z, fmaf(a2.w, bv.w, acc[2][j]))));
                acc[3][j] = fmaf(a3.x, bv.x, fmaf(a3.y, bv.y, fmaf(a3.z, bv.z, fmaf(a3.w, bv.w, acc[3][j]))));
            }
        }
        if ((tt & 3) == 3) {
            const int c0 = (tt >> 2) << 8;
#pragma unroll
            for (int i = 0; i < 4; ++i)
#pragma unroll
                for (int j = 0; j < 4; ++j)
                    S[rg4 + i][c0 + lane + (j << 6)] = acc[i][j] * 0.125f;
        }
    }
    __syncthreads();

    // phase B: per wave, 4 rows; exact 64th-largest via bit bisection
    for (int q = 0; q < 4; ++q) {
        const int r = rg4 + q;
        float    fv[32];
        unsigned uv[32];
#pragma unroll
        for (int m = 0; m < 32; ++m) {
            float x = S[r][lane + (m << 6)];
            fv[m] = x;
            unsigned bx = __float_as_uint(x);
            uv[m] = bx ^ (unsigned)(((int)bx >> 31) | 0x80000000);
        }
        unsigned lo = 0;
#pragma unroll 1
        for (int bit = 31; bit >= 0; --bit) {
            unsigned mid = lo | (1u << bit);
            int c = 0;
#pragma unroll
            for (int m = 0; m < 32; ++m) {
                unsigned long long ball = __ballot(uv[m] >= mid);
                c += __popcll(ball);
            }
            if (c >= 64) lo = mid;   // uniform (ballot count is wave-uniform)
        }
        // row max (always kept, so Z >= 1)
        unsigned um = 0;
#pragma unroll
        for (int m = 0; m < 32; ++m) um = uv[m] > um ? uv[m] : um;
#pragma unroll
        for (int off = 1; off < 64; off <<= 1) {
            unsigned o = (unsigned)__shfl_xor((int)um, off, 64);
            um = o > um ? o : um;
        }
        unsigned mb = (um & 0x80000000u) ? (um ^ 0x80000000u) : ~um;
        float Mx = __uint_as_float(mb);

        float zs = 0.f;
#pragma unroll
        for (int m = 0; m < 32; ++m) {
            bool keep = uv[m] >= lo;
            float ex = keep ? __expf(fv[m] - Mx) : 0.f;
            fv[m] = ex;
            zs += ex;
        }
#pragma unroll
        for (int off = 1; off < 64; off <<= 1) zs += __shfl_xor(zs, off, 64);
        float zinv = 1.0f / zs;

        const size_t grow = (size_t)bh * 2048 + r0 + r;
        float* vd          = svals + grow * SLOTS;
        unsigned short* id = sidx  + grow * SLOTS;
        const unsigned long long pre = (1ull << lane) - 1ull;
        int base = 0;
#pragma unroll 1
        for (int m = 0; m < 32; ++m) {
            bool keep = uv[m] >= lo;
            unsigned long long ball = __ballot(keep);
            if (keep) {
                int my = base + __popcll(ball & pre);
                if (my < SLOTS) {
                    vd[my] = fv[m] * zinv;
                    id[my] = (unsigned short)(lane + (m << 6));
                }
            }
            base += __popcll(ball);
        }
        if (lane == 0) scnt[grow] = base < SLOTS ? base : SLOTS;
    }
}

// ---------------------------------------------------------------------------
// K3: sparse attn application. One wave per row: acc_d = sum_j val_j * v[idx_j][d]
// order 0 reads v from qkv (stride 1536), orders 1,2 read dense (bh,n,64) buf.
// res(b,n,inner) gets += gelu(alpha_raw) * acc  (written, not +=, at order 0).
// ---------------------------------------------------------------------------
__global__ __launch_bounds__(256)
void spmm(const float* __restrict__ svals, const unsigned short* __restrict__ sidx,
          const int* __restrict__ scnt, const float* __restrict__ qkv,
          const float* __restrict__ vin, float* __restrict__ vout,
          float* __restrict__ res, const float* __restrict__ alphas_raw, int order)
{
    const int lane = threadIdx.x & 63;
    const int gr   = (blockIdx.x << 2) + (threadIdx.x >> 6);  // 0..65535
    const int bh   = gr >> 11, n = gr & 2047;
    const int b    = bh >> 3,  h = bh & 7;

    const float* vb;
    int stride;
    if (order == 0) { vb = qkv + (size_t)b * 2048 * 1536 + 1024 + (h << 6); stride = 1536; }
    else            { vb = vin + ((size_t)bh << 17);                        stride = 64;   }

    const int cnt = scnt[gr];
    const float* va          = svals + (size_t)gr * SLOTS;
    const unsigned short* ia = sidx  + (size_t)gr * SLOTS;

    float acc = 0.f;
    int j = 0;
    for (; j + 4 <= cnt; j += 4) {
        float a0 = va[j], a1 = va[j + 1], a2 = va[j + 2], a3 = va[j + 3];
        int   i0 = ia[j], i1 = ia[j + 1], i2 = ia[j + 2], i3 = ia[j + 3];
        acc += a0 * vb[(size_t)i0 * stride + lane];
        acc += a1 * vb[(size_t)i1 * stride + lane];
        acc += a2 * vb[(size_t)i2 * stride + lane];
        acc += a3 * vb[(size_t)i3 * stride + lane];
    }
    for (; j < cnt; ++j) acc += va[j] * vb[(size_t)ia[j] * stride + lane];

    if (order < 2) vout[((size_t)gr << 6) + lane] = acc;

    float ar    = alphas_raw[(order << 3) + h];
    float alpha = ar * 0.5f * (1.0f + erff(ar * 0.70710678f));  // exact gelu
    size_t ro = ((size_t)b * 2048 + n) * 512 + (h << 6) + lane;
    float av  = alpha * acc;
    if (order == 0) res[ro] = av;
    else            res[ro] += av;
}

// ---------------------------------------------------------------------------
extern "C" void kernel_launch(void* const* d_in, const int* in_sizes, int n_in,
                              void* d_out, int out_size, void* d_ws, size_t ws_size,
                              hipStream_t stream)
{
    const float* x      = (const float*)d_in[0];
    const float* Wqkv   = (const float*)d_in[1];
    const float* bqkv   = (const float*)d_in[2];
    const float* Wout   = (const float*)d_in[3];
    const float* bout   = (const float*)d_in[4];
    const float* alphas = (const float*)d_in[5];
    float* out = (float*)d_out;

    // workspace layout (bytes)
    char* ws = (char*)d_ws;
    float*          qkvb  = (float*)ws;                       // 8192*1536*4 = 50331648
    float*          svals = (float*)(ws + 50331648);          // 65536*80*4  = 20971520
    unsigned short* sidxp = (unsigned short*)(ws + 71303168); // 65536*80*2  = 10485760
    int*            scntp = (int*)(ws + 81788928);            // 65536*4     = 262144
    float*          v1    = (float*)(ws + 82051072);          // 16777216
    float*          v2    = (float*)(ws + 98828288);          // 16777216
    float*          resb  = (float*)(ws + 115605504);         // 16777216
    if (ws_size < 132382720) return;                          // need ~126 MB

    // K1: qkv = x @ Wqkv + bqkv
    sgemm_bias<<<dim3(1536 / 64, 8192 / 64), 256, 0, stream>>>(
        x, Wqkv, bqkv, qkvb, 8192, 1536, 512);

    // K2: scores -> exact top-64(+ties) -> softmax -> sparse rows
    scores_topk<<<dim3(128, 32), 256, 0, stream>>>(qkvb, svals, sidxp, scntp);

    // K3 x3: polynomial filter (sparse A applications)
    spmm<<<16384, 256, 0, stream>>>(svals, sidxp, scntp, qkvb, nullptr, v1, resb, alphas, 0);
    spmm<<<16384, 256, 0, stream>>>(svals, sidxp, scntp, qkvb, v1, v2, resb, alphas, 1);
    spmm<<<16384, 256, 0, stream>>>(svals, sidxp, scntp, qkvb, v2, nullptr, resb, alphas, 2);

    // K4: out = res @ Wout + bout
    sgemm_bias<<<dim3(512 / 64, 8192 / 64), 256, 0, stream>>>(
        resb, Wout, bout, out, 8192, 512, 512);
}

// Round 2
// 2308.310 us; speedup vs baseline: 1.0456x; 1.0456x over previous
//
#include <hip/hip_runtime.h>
#include <hip/hip_bf16.h>

// Problem constants: B=4, N=2048, DIM=512, H=8, DH=64, ORDER=3, TOPK=64, INNER=512
#define SLOTS 80   // sparse slots per row (64 + tie headroom)

// ---------------------------------------------------------------------------
// K1/K4: fp32 tiled GEMM with bias: C = A(MxK) @ B(KxN) + bias(N)
// BM=BN=128, BK=16, 256 threads, 8x8 per thread.
// Bit-identical to the 64x64 version: per-output-element accumulation is a
// strictly sequential fmaf chain over k=0..K-1, bias added once at the end.
// ---------------------------------------------------------------------------
__global__ __launch_bounds__(256)
void sgemm_bias(const float* __restrict__ A, const float* __restrict__ Bm,
                const float* __restrict__ bias, float* __restrict__ C,
                int M, int N, int K)
{
    __shared__ float As[16][132];   // [k][m], padded
    __shared__ float Bs[16][132];   // [k][n], padded

    const int t  = threadIdx.x;
    const int tx = t & 15, ty = t >> 4;
    const int bm = blockIdx.y << 7, bn = blockIdx.x << 7;

    // staging maps
    const int arow = t >> 2,  ak4 = (t & 3) << 2;    // A: 64 rows/pass, 2 passes
    const int bkr  = t >> 5,  bc4 = (t & 31) << 2;   // B: 8 k-rows/pass, 2 passes

    float4 pa[2], pb[2];
#pragma unroll
    for (int s = 0; s < 2; ++s) {
        pa[s] = *(const float4*)&A[(size_t)(bm + arow + (s << 6)) * K + ak4];
        pb[s] = *(const float4*)&Bm[(size_t)(bkr + (s << 3)) * N + bn + bc4];
    }

    float acc[8][8] = {};

    for (int k0 = 0; k0 < K; k0 += 16) {
        __syncthreads();
#pragma unroll
        for (int s = 0; s < 2; ++s) {
            const int ar = arow + (s << 6);
            As[ak4 + 0][ar] = pa[s].x;
            As[ak4 + 1][ar] = pa[s].y;
            As[ak4 + 2][ar] = pa[s].z;
            As[ak4 + 3][ar] = pa[s].w;
            *(float4*)&Bs[bkr + (s << 3)][bc4] = pb[s];
        }
        __syncthreads();
        if (k0 + 16 < K) {
#pragma unroll
            for (int s = 0; s < 2; ++s) {
                pa[s] = *(const float4*)&A[(size_t)(bm + arow + (s << 6)) * K + k0 + 16 + ak4];
                pb[s] = *(const float4*)&Bm[(size_t)(k0 + 16 + bkr + (s << 3)) * N + bn + bc4];
            }
        }
#pragma unroll
        for (int kk = 0; kk < 16; ++kk) {
            float4 a0 = *(const float4*)&As[kk][(ty << 3) + 0];
            float4 a1 = *(const float4*)&As[kk][(ty << 3) + 4];
            float4 b0 = *(const float4*)&Bs[kk][(tx << 2)];
            float4 b1 = *(const float4*)&Bs[kk][64 + (tx << 2)];
            float ar[8] = {a0.x, a0.y, a0.z, a0.w, a1.x, a1.y, a1.z, a1.w};
            float br[8] = {b0.x, b0.y, b0.z, b0.w, b1.x, b1.y, b1.z, b1.w};
#pragma unroll
            for (int i = 0; i < 8; ++i)
#pragma unroll
                for (int j = 0; j < 8; ++j)
                    acc[i][j] = fmaf(ar[i], br[j], acc[i][j]);
        }
    }

    float bb[8];
#pragma unroll
    for (int j = 0; j < 4; ++j) {
        bb[j]     = bias[bn + (tx << 2) + j];
        bb[j + 4] = bias[bn + 64 + (tx << 2) + j];
    }
#pragma unroll
    for (int i = 0; i < 8; ++i) {
        const size_t row = (size_t)(bm + (ty << 3) + i);
        float4 o0 = {acc[i][0] + bb[0], acc[i][1] + bb[1], acc[i][2] + bb[2], acc[i][3] + bb[3]};
        float4 o1 = {acc[i][4] + bb[4], acc[i][5] + bb[5], acc[i][6] + bb[6], acc[i][7] + bb[7]};
        *(float4*)&C[row * N + bn + (tx << 2)]      = o0;
        *(float4*)&C[row * N + bn + 64 + (tx << 2)] = o1;
    }
}

// ---------------------------------------------------------------------------
// K2: per-(b,h), 8 rows/block. QK^T with 32-col XOR-swizzled k tiles
// (conflict-free LDS), scores to 64KB LDS S, then exact top-64(+ties) via
// uint bisection, softmax, sparse compaction.  LDS total 74 KB -> 2 blocks/CU.
// Accumulation order per score: d strictly ascending 0..63 (bit-identical).
// ---------------------------------------------------------------------------
__global__ __launch_bounds__(256)
void scores_topk(const float* __restrict__ qkv, float* __restrict__ svals,
                 unsigned short* __restrict__ sidx, int* __restrict__ scnt)
{
    __shared__ float S[8][2048];   // 64 KB scores
    __shared__ float kt[2048];     // 8 KB: 32 cols x 64 d, 16B-slot swizzled
    __shared__ float qs[8][64];    // 2 KB

    const int t    = threadIdx.x;
    const int lane = t & 63;
    const int wid  = t >> 6;
    const int bh   = blockIdx.y;
    const int b    = bh >> 3, h = bh & 7;
    const int r0   = blockIdx.x << 3;
    const size_t rowbase = (size_t)b * 2048;
    const int qoff = h << 6;
    const int koff = 512 + (h << 6);

    // stage q: 8 rows x 64 floats
    if (t < 128) {
        const int row = t >> 4, d4 = (t & 15) << 2;
        *(float4*)&qs[row][d4] =
            *(const float4*)&qkv[(rowbase + r0 + row) * 1536 + qoff + d4];
    }

    // k staging map: pass s: col c = (t>>4)+16s, d-chunk dd = t&15
    const int sc0 = t >> 4;
    const int sdd = t & 15;

    float4 pre[2];
#pragma unroll
    for (int s = 0; s < 2; ++s)
        pre[s] = *(const float4*)&qkv[(rowbase + sc0 + (s << 4)) * 1536 + koff + (sdd << 2)];

    const int cl  = lane & 31;                 // col within tile
    const int rr  = (wid << 1) + (lane >> 5);  // this half-wave's row (0..7)
    const int swz = cl & 7;

    for (int tt = 0; tt < 64; ++tt) {
        __syncthreads();   // previous tile's readers done
#pragma unroll
        for (int s = 0; s < 2; ++s) {
            const int c = sc0 + (s << 4);
            *(float4*)&kt[(c << 6) + ((sdd ^ (c & 7)) << 2)] = pre[s];
        }
        __syncthreads();   // tile ready
        if (tt < 63) {
            const int c0n = (tt + 1) << 5;
#pragma unroll
            for (int s = 0; s < 2; ++s)
                pre[s] = *(const float4*)
                    &qkv[(rowbase + c0n + sc0 + (s << 4)) * 1536 + koff + (sdd << 2)];
        }
        float acc = 0.f;
#pragma unroll
        for (int dd = 0; dd < 16; ++dd) {
            float4 k4 = *(const float4*)&kt[(cl << 6) + ((dd ^ swz) << 2)];
            float4 q4 = *(const float4*)&qs[rr][dd << 2];
            acc = fmaf(q4.x, k4.x, acc);
            acc = fmaf(q4.y, k4.y, acc);
            acc = fmaf(q4.z, k4.z, acc);
            acc = fmaf(q4.w, k4.w, acc);
        }
        S[rr][(tt << 5) + cl] = acc * 0.125f;
    }
    __syncthreads();

    // phase B: per wave, 2 rows; exact 64th-largest via bit bisection
    for (int q = 0; q < 2; ++q) {
        const int r = (wid << 1) + q;
        float    fv[32];
        unsigned uv[32];
#pragma unroll
        for (int m = 0; m < 32; ++m) {
            float x = S[r][lane + (m << 6)];
            fv[m] = x;
            unsigned bx = __float_as_uint(x);
            uv[m] = bx ^ (unsigned)(((int)bx >> 31) | 0x80000000);
        }
        unsigned lo = 0;
#pragma unroll 1
        for (int bit = 31; bit >= 0; --bit) {
            unsigned mid = lo | (1u << bit);
            int c = 0;
#pragma unroll
            for (int m = 0; m < 32; ++m) {
                unsigned long long ball = __ballot(uv[m] >= mid);
                c += __popcll(ball);
            }
            if (c >= 64) lo = mid;   // uniform (ballot count is wave-uniform)
        }
        // row max (always kept, so Z >= 1)
        unsigned um = 0;
#pragma unroll
        for (int m = 0; m < 32; ++m) um = uv[m] > um ? uv[m] : um;
#pragma unroll
        for (int off = 1; off < 64; off <<= 1) {
            unsigned o = (unsigned)__shfl_xor((int)um, off, 64);
            um = o > um ? o : um;
        }
        unsigned mb = (um & 0x80000000u) ? (um ^ 0x80000000u) : ~um;
        float Mx = __uint_as_float(mb);

        float zs = 0.f;
#pragma unroll
        for (int m = 0; m < 32; ++m) {
            bool keep = uv[m] >= lo;
            float ex = keep ? __expf(fv[m] - Mx) : 0.f;
            fv[m] = ex;
            zs += ex;
        }
#pragma unroll
        for (int off = 1; off < 64; off <<= 1) zs += __shfl_xor(zs, off, 64);
        float zinv = 1.0f / zs;

        const size_t grow = (size_t)bh * 2048 + r0 + r;
        float* vd          = svals + grow * SLOTS;
        unsigned short* id = sidx  + grow * SLOTS;
        const unsigned long long pre64 = (1ull << lane) - 1ull;
        int base = 0;
#pragma unroll 1
        for (int m = 0; m < 32; ++m) {
            bool keep = uv[m] >= lo;
            unsigned long long ball = __ballot(keep);
            if (keep) {
                int my = base + __popcll(ball & pre64);
                if (my < SLOTS) {
                    vd[my] = fv[m] * zinv;
                    id[my] = (unsigned short)(lane + (m << 6));
                }
            }
            base += __popcll(ball);
        }
        if (lane == 0) scnt[grow] = base < SLOTS ? base : SLOTS;
    }
}

// ---------------------------------------------------------------------------
// K3: sparse attn application. One wave per row: acc_d = sum_j val_j * v[idx_j][d]
// ---------------------------------------------------------------------------
__global__ __launch_bounds__(256)
void spmm(const float* __restrict__ svals, const unsigned short* __restrict__ sidx,
          const int* __restrict__ scnt, const float* __restrict__ qkv,
          const float* __restrict__ vin, float* __restrict__ vout,
          float* __restrict__ res, const float* __restrict__ alphas_raw, int order)
{
    const int lane = threadIdx.x & 63;
    const int gr   = (blockIdx.x << 2) + (threadIdx.x >> 6);  // 0..65535
    const int bh   = gr >> 11, n = gr & 2047;
    const int b    = bh >> 3,  h = bh & 7;

    const float* vb;
    int stride;
    if (order == 0) { vb = qkv + (size_t)b * 2048 * 1536 + 1024 + (h << 6); stride = 1536; }
    else            { vb = vin + ((size_t)bh << 17);                        stride = 64;   }

    const int cnt = scnt[gr];
    const float* va          = svals + (size_t)gr * SLOTS;
    const unsigned short* ia = sidx  + (size_t)gr * SLOTS;

    float acc = 0.f;
    int j = 0;
    for (; j + 4 <= cnt; j += 4) {
        float a0 = va[j], a1 = va[j + 1], a2 = va[j + 2], a3 = va[j + 3];
        int   i0 = ia[j], i1 = ia[j + 1], i2 = ia[j + 2], i3 = ia[j + 3];
        acc += a0 * vb[(size_t)i0 * stride + lane];
        acc += a1 * vb[(size_t)i1 * stride + lane];
        acc += a2 * vb[(size_t)i2 * stride + lane];
        acc += a3 * vb[(size_t)i3 * stride + lane];
    }
    for (; j < cnt; ++j) acc += va[j] * vb[(size_t)ia[j] * stride + lane];

    if (order < 2) vout[((size_t)gr << 6) + lane] = acc;

    float ar    = alphas_raw[(order << 3) + h];
    float alpha = ar * 0.5f * (1.0f + erff(ar * 0.70710678f));  // exact gelu
    size_t ro = ((size_t)b * 2048 + n) * 512 + (h << 6) + lane;
    float av  = alpha * acc;
    if (order == 0) res[ro] = av;
    else            res[ro] += av;
}

// ---------------------------------------------------------------------------
extern "C" void kernel_launch(void* const* d_in, const int* in_sizes, int n_in,
                              void* d_out, int out_size, void* d_ws, size_t ws_size,
                              hipStream_t stream)
{
    const float* x      = (const float*)d_in[0];
    const float* Wqkv   = (const float*)d_in[1];
    const float* bqkv   = (const float*)d_in[2];
    const float* Wout   = (const float*)d_in[3];
    const float* bout   = (const float*)d_in[4];
    const float* alphas = (const float*)d_in[5];
    float* out = (float*)d_out;

    // workspace layout (bytes)
    char* ws = (char*)d_ws;
    float*          qkvb  = (float*)ws;                       // 8192*1536*4 = 50331648
    float*          svals = (float*)(ws + 50331648);          // 65536*80*4  = 20971520
    unsigned short* sidxp = (unsigned short*)(ws + 71303168); // 65536*80*2  = 10485760
    int*            scntp = (int*)(ws + 81788928);            // 65536*4     = 262144
    float*          v1    = (float*)(ws + 82051072);          // 16777216
    float*          v2    = (float*)(ws + 98828288);          // 16777216
    float*          resb  = (float*)(ws + 115605504);         // 16777216
    if (ws_size < 132382720) return;                          // need ~126 MB

    // K1: qkv = x @ Wqkv + bqkv
    sgemm_bias<<<dim3(1536 / 128, 8192 / 128), 256, 0, stream>>>(
        x, Wqkv, bqkv, qkvb, 8192, 1536, 512);

    // K2: scores -> exact top-64(+ties) -> softmax -> sparse rows
    scores_topk<<<dim3(256, 32), 256, 0, stream>>>(qkvb, svals, sidxp, scntp);

    // K3 x3: polynomial filter (sparse A applications)
    spmm<<<16384, 256, 0, stream>>>(svals, sidxp, scntp, qkvb, nullptr, v1, resb, alphas, 0);
    spmm<<<16384, 256, 0, stream>>>(svals, sidxp, scntp, qkvb, v1, v2, resb, alphas, 1);
    spmm<<<16384, 256, 0, stream>>>(svals, sidxp, scntp, qkvb, v2, nullptr, resb, alphas, 2);

    // K4: out = res @ Wout + bout
    sgemm_bias<<<dim3(512 / 128, 8192 / 128), 256, 0, stream>>>(
        resb, Wout, bout, out, 8192, 512, 512);
}